// Round 1
// baseline (1083.150 us; speedup 1.0000x reference)
//
#include <hip/hip_runtime.h>
#include <hip/hip_bf16.h>

typedef short short8 __attribute__((ext_vector_type(8)));
typedef short short4v __attribute__((ext_vector_type(4)));
typedef float f32x4 __attribute__((ext_vector_type(4)));
typedef __bf16 bf16x8 __attribute__((ext_vector_type(8)));

#define DEVI static __device__ __forceinline__

#if __has_builtin(__builtin_amdgcn_exp2f)
#define EXP2(x) __builtin_amdgcn_exp2f(x)
#else
#define EXP2(x) exp2f(x)
#endif
#if __has_builtin(__builtin_amdgcn_rcpf)
#define RCP(x) __builtin_amdgcn_rcpf(x)
#else
#define RCP(x) (1.0f / (x))
#endif

static constexpr int BB = 256, TT = 512, DIN0 = 40, HH = 128, NCLS = 7;
static constexpr int NB = 16;     // batch rows per workgroup
static constexpr int NTHR = 512;  // 8 waves
static constexpr float L2E = 1.44269504088896f;

DEVI short f2b(float x) {
  union { __hip_bfloat16 h; short s; } u;
  u.h = __float2bfloat16(x);
  return u.s;
}

DEVI bf16x8 as_bf(short8 s) { return __builtin_bit_cast(bf16x8, s); }

// One WG = (direction, 16-batch tile). Holds W as bf16 MFMA A-fragments in
// VGPRs for all 512 steps; per step computes g = W @ [x_t ; h_{t-1}] + b with
// mfma_f32_16x16x32_bf16, then the LSTM cell update in fp32.
// Wave w owns rows [16w,16w+16) of each gate block i/f/g/o, so every lane has
// the 4 gates of its 4 cells locally (C/D layout: col=lane&15, row=(lane>>4)*4+r).
template <bool L0>
__global__ __launch_bounds__(NTHR, 2) void lstm_kernel(
    const float* __restrict__ x0, const short* __restrict__ h1_in,
    const float* __restrict__ Wih_f, const float* __restrict__ Whh_f,
    const float* __restrict__ bias_f, const float* __restrict__ Wih_r,
    const float* __restrict__ Whh_r, const float* __restrict__ bias_r,
    short* __restrict__ h1_out, float* __restrict__ h2last) {
  constexpr int K0 = L0 ? 64 : 256;   // padded x-part of K
  constexpr int DI = L0 ? DIN0 : 256; // real x dim
  constexpr int KT = K0 + HH;         // total K (192 / 384)
  constexpr int KF = KT / 32;         // k-fragments (6 / 12)
  constexpr int RS = KT + 8;          // LDS row stride: *2B = 400/784B, 16B-aligned, +4 banks/row

  __shared__ short Bbuf[2][NB][RS];

  const int tid = threadIdx.x;
  const int w = tid >> 6;
  const int lane = tid & 63;
  const int lg = lane >> 4;
  const int bcol = lane & 15;
  const int dir = blockIdx.x & 1;
  const int b0 = (blockIdx.x >> 1) * NB;

  const float* __restrict__ Wih = dir ? Wih_r : Wih_f;
  const float* __restrict__ Whh = dir ? Whh_r : Whh_f;
  const float* __restrict__ bias = dir ? bias_r : bias_f;

  // ---- W fragments, VGPR-resident for the whole kernel ----
  // A-frag (16x16x32): row m = lane&15, k = (lane>>4)*8 + e.
  // Pre-scale: i,f,o rows by -log2e (sigmoid via exp2), g rows by +2*log2e (tanh via exp2).
  short8 wfrag[4][KF];
#pragma unroll
  for (int q = 0; q < 4; ++q) {
    const float scale = (q == 2) ? (2.0f * L2E) : (-L2E);
    const int m = q * HH + w * 16 + bcol;
#pragma unroll
    for (int kk = 0; kk < KF; ++kk) {
      short8 f;
#pragma unroll
      for (int e = 0; e < 8; ++e) {
        const int k = kk * 32 + lg * 8 + e;
        float v = 0.0f;
        if (k < K0) {
          if (k < DI) v = Wih[(size_t)m * DI + k];
        } else {
          v = Whh[(size_t)m * HH + (k - K0)];
        }
        f[e] = f2b(v * scale);
      }
      wfrag[q][kk] = f;
    }
  }

  f32x4 bq[4];
#pragma unroll
  for (int q = 0; q < 4; ++q) {
    const float scale = (q == 2) ? (2.0f * L2E) : (-L2E);
#pragma unroll
    for (int r = 0; r < 4; ++r)
      bq[q][r] = bias[q * HH + w * 16 + lg * 4 + r] * scale;
  }

  // zero LDS: initial h state + padding columns (must not be NaN garbage)
  for (int i = tid; i < 2 * NB * RS; i += NTHR) (&Bbuf[0][0][0])[i] = 0;
  __syncthreads();

  // stage x for step 0 into buffer 0
  {
    const int t0 = dir ? (TT - 1) : 0;
    if constexpr (L0) {
      if (tid < 160) {
        const int bl = tid / 10, c4 = tid % 10;
        f32x4 v = *(const f32x4*)(x0 + ((size_t)(b0 + bl) * TT + t0) * DI + c4 * 4);
        short4v o;
        o[0] = f2b(v[0]); o[1] = f2b(v[1]); o[2] = f2b(v[2]); o[3] = f2b(v[3]);
        *(short4v*)&Bbuf[0][bl][c4 * 4] = o;
      }
    } else {
      const int bl = tid >> 5, seg = tid & 31;
      short8 v = *(const short8*)(h1_in + ((size_t)(b0 + bl) * TT + t0) * 256 + seg * 8);
      *(short8*)&Bbuf[0][bl][seg * 8] = v;
    }
  }
  __syncthreads();

  f32x4 cst = {0.f, 0.f, 0.f, 0.f};

  for (int s = 0; s < TT; ++s) {
    const int cur = s & 1;
    const int t = dir ? (TT - 1 - s) : s;
    const bool st = (s + 1 < TT);

    // ---- issue global loads for next step's x (latency hides under MFMAs) ----
    f32x4 xf;
    short8 xh;
    if (st) {
      const int tn = dir ? (TT - 2 - s) : (s + 1);
      if constexpr (L0) {
        if (tid < 160)
          xf = *(const f32x4*)(x0 + ((size_t)(b0 + tid / 10) * TT + tn) * DI + (tid % 10) * 4);
      } else {
        xh = *(const short8*)(h1_in + ((size_t)(b0 + (tid >> 5)) * TT + tn) * 256 + (tid & 31) * 8);
      }
    }

    // ---- MFMA: acc = W @ [x_t ; h_{t-1}] + b ----
    f32x4 acc[4] = {bq[0], bq[1], bq[2], bq[3]};
#pragma unroll
    for (int kk = 0; kk < KF; ++kk) {
      const bf16x8 bf = as_bf(*(const short8*)&Bbuf[cur][bcol][kk * 32 + lg * 8]);
#pragma unroll
      for (int q = 0; q < 4; ++q)
        acc[q] = __builtin_amdgcn_mfma_f32_16x16x32_bf16(as_bf(wfrag[q][kk]), bf, acc[q], 0, 0, 0);
    }

    // ---- write staged x into next buffer (region disjoint from current reads) ----
    if (st) {
      if constexpr (L0) {
        if (tid < 160) {
          short4v o;
          o[0] = f2b(xf[0]); o[1] = f2b(xf[1]); o[2] = f2b(xf[2]); o[3] = f2b(xf[3]);
          *(short4v*)&Bbuf[cur ^ 1][tid / 10][(tid % 10) * 4] = o;
        }
      } else {
        *(short8*)&Bbuf[cur ^ 1][tid >> 5][(tid & 31) * 8] = xh;
      }
    }

    // ---- cell update (fp32): sigmoid/tanh via exp2 on pre-scaled activations ----
    short4v hp;
    f32x4 hf;
#pragma unroll
    for (int r = 0; r < 4; ++r) {
      const float ig = RCP(1.0f + EXP2(acc[0][r]));
      const float fg = RCP(1.0f + EXP2(acc[1][r]));
      float tg = EXP2(acc[2][r]);
      tg = 1.0f - 2.0f * RCP(tg + 1.0f);
      const float og = RCP(1.0f + EXP2(acc[3][r]));
      const float cn = fg * cst[r] + ig * tg;
      cst[r] = cn;
      float tc = EXP2(cn * (2.0f * L2E));
      tc = 1.0f - 2.0f * RCP(tc + 1.0f);
      const float hv = og * tc;
      hf[r] = hv;
      hp[r] = f2b(hv);
    }
    const int j0 = w * 16 + lg * 4;
    *(short4v*)&Bbuf[cur ^ 1][bcol][K0 + j0] = hp;  // h_t for next step

    if constexpr (L0) {
      // emit h1[b][t][dir*128 + j] (bf16) for layer 1
      *(short4v*)(h1_out + (((size_t)(b0 + bcol) * TT + t) * 256) + dir * HH + j0) = hp;
    } else {
      // only h2 at t = T-1 is consumed: fwd's last step, rev's first step
      if ((dir == 0 && s == TT - 1) || (dir == 1 && s == 0)) {
        *(f32x4*)(h2last + (size_t)(b0 + bcol) * 256 + dir * HH + j0) = hf;
      }
    }
    __syncthreads();
  }
}

__global__ void fc_kernel(const float* __restrict__ h2last,
                          const float* __restrict__ fcw,
                          const float* __restrict__ fcb,
                          float* __restrict__ out) {
  const int gid = blockIdx.x * blockDim.x + threadIdx.x;
  if (gid >= BB * NCLS) return;
  const int b = gid / NCLS, n = gid % NCLS;
  const float* hp = h2last + (size_t)b * 256;
  const float* wp = fcw + (size_t)n * 256;
  float s = fcb[n];
#pragma unroll 8
  for (int j = 0; j < 256; ++j) s = fmaf(hp[j], wp[j], s);
  out[gid] = s;
}

extern "C" void kernel_launch(void* const* d_in, const int* in_sizes, int n_in,
                              void* d_out, int out_size, void* d_ws, size_t ws_size,
                              hipStream_t stream) {
  const float* x     = (const float*)d_in[0];
  const float* Wih0f = (const float*)d_in[1];
  const float* Whh0f = (const float*)d_in[2];
  const float* b0f   = (const float*)d_in[3];
  const float* Wih0r = (const float*)d_in[4];
  const float* Whh0r = (const float*)d_in[5];
  const float* b0r   = (const float*)d_in[6];
  const float* Wih1f = (const float*)d_in[7];
  const float* Whh1f = (const float*)d_in[8];
  const float* b1f   = (const float*)d_in[9];
  const float* Wih1r = (const float*)d_in[10];
  const float* Whh1r = (const float*)d_in[11];
  const float* b1r   = (const float*)d_in[12];
  const float* fcw   = (const float*)d_in[13];
  const float* fcb   = (const float*)d_in[14];

  short* h1 = (short*)d_ws;                                           // [B][T][256] bf16, 64 MB
  float* h2last = (float*)((char*)d_ws + (size_t)BB * TT * 256 * 2);  // [B][256] f32

  lstm_kernel<true><<<dim3(32), dim3(NTHR), 0, stream>>>(
      x, nullptr, Wih0f, Whh0f, b0f, Wih0r, Whh0r, b0r, h1, nullptr);
  lstm_kernel<false><<<dim3(32), dim3(NTHR), 0, stream>>>(
      nullptr, h1, Wih1f, Whh1f, b1f, Wih1r, Whh1r, b1r, nullptr, h2last);
  fc_kernel<<<dim3((BB * NCLS + 255) / 256), dim3(256), 0, stream>>>(
      h2last, fcw, fcb, (float*)d_out);
}